// Round 7
// baseline (190.369 us; speedup 1.0000x reference)
//
#include <hip/hip_runtime.h>
#include <hip/hip_bf16.h>

#define B_    32
#define LD_   512
#define LQ_   32
#define E_    300
#define NF_   4
#define D_    304
#define M_    16
#define ALPHA_ 0.9f
#define CIN_  1212          // 3*D + E
#define KP1_  1216          // CIN padded to multiple of 64
#define NCOL_ 1056          // 33 columns * 32 batches
#define NPAD_ 1088          // 17 * 64
#define PPL_  9
#define NEG_N_ 128

typedef short short8 __attribute__((ext_vector_type(8)));
typedef float f32x4 __attribute__((ext_vector_type(4)));

__device__ __constant__ float A_POW[32] = {
    1.0f, 0.9f, 0.81f, 0.729f, 0.6561f, 0.59049f, 0.531441f, 0.4782969f,
    0.43046721f, 0.387420489f, 0.3486784401f, 0.31381059609f,
    0.282429536481f, 0.2541865828329f, 0.22876792454961f, 0.205891132094649f,
    0.18530201888518416f, 0.16677181699666577f, 0.1500946352969992f,
    0.13508517176729928f, 0.12157665459056935f, 0.10941898913151242f,
    0.09847709021836118f, 0.08862938119652507f, 0.07976644307687256f,
    0.0717897987691853f, 0.06461081889226677f, 0.05814973700304009f,
    0.05233476330273608f, 0.047101286972462474f, 0.042391158275216226f,
    0.038152042447694604f
};

__device__ __forceinline__ unsigned short f2bf(float f) {
    unsigned int x = __float_as_uint(f);
    unsigned int r = (x + 0x7FFFu + ((x >> 16) & 1u)) >> 16;
    return (unsigned short)r;
}

// ---------------------------------------------------------------------------
// prep: blockIdx branches
//   [0,1056)    feature columns (query FOFE inlined, alpha table)
//   [1056,2000) weight fp32->bf16 (grid-stride)
//   [2000,2032) zero Ft pad rows
//   2032        zero zbuf + done counter
// ---------------------------------------------------------------------------
__global__ __launch_bounds__(320) void prep(
    const int* __restrict__ doc, const float* __restrict__ doc_f,
    const int* __restrict__ query,
    const int* __restrict__ target_s, const int* __restrict__ target_e,
    const float* __restrict__ emb,
    const int* __restrict__ rand_length, const int* __restrict__ rand_position,
    const float* __restrict__ W1, const float* __restrict__ W2,
    const float* __restrict__ W3, const float* __restrict__ W4,
    unsigned short* __restrict__ W1b, unsigned short* __restrict__ W2b,
    unsigned short* __restrict__ W3b, unsigned short* __restrict__ W4b,
    unsigned short* __restrict__ Ft, float* __restrict__ zbuf,
    unsigned* __restrict__ done)
{
    int bid = blockIdx.x;
    int tid = threadIdx.x;

    if (bid < NCOL_) {
        int b = bid / 33;
        int col = bid % 33;
        __shared__ int   s_t[3][16];
        __shared__ float s_w[3][16];
        __shared__ int   s_row[3][16];
        if (tid < 48) {
            int part = tid >> 4, k = tid & 15;
            int t; float valid;
            if (col == 0) {
                int ts = target_s[b], te = target_e[b];
                int span = te - ts;
                if (part == 0)      { t = ts - 1 - k;  valid = (t >= 0) ? 1.f : 0.f; }
                else if (part == 1) { t = te - k;      valid = (k <= span && t >= 0) ? 1.f : 0.f; }
                else                { t = te + 1 + k;  valid = (t < LD_) ? 1.f : 0.f; }
            } else {
                int j = col - 1;
                int r = j / PPL_, p = j - r * PPL_;
                int rl = rand_length[r];
                int rp = rand_position[r * PPL_ + p];
                if (part == 0)      { t = rp - 1 - k;      valid = (t >= 0) ? 1.f : 0.f; }
                else if (part == 1) { t = rp - k;          valid = (k <= rl && t >= 0) ? 1.f : 0.f; }
                else                { t = rp + rl + 1 + k; valid = (t < LD_) ? 1.f : 0.f; }
            }
            float w = (valid != 0.f) ? A_POW[k] : 0.f;
            t = min(max(t, 0), LD_ - 1);
            s_t[part][k] = t;
            s_w[part][k] = w;
            s_row[part][k] = doc[b * LD_ + t];
        }
        __syncthreads();

        unsigned short* out = Ft + (size_t)bid * KP1_;
        int g = tid;                       // 304 groups of 4 elements (K=1216)
        if (g < 228) {                     // doc parts: 3 * 76 groups
            int part = g / 76;
            int g2 = g - part * 76;
            int cc = g2 * 4;
            float ax = 0.f, ay = 0.f, az = 0.f, aw = 0.f;
            if (cc < 300) {
                for (int i = 0; i < 16; ++i) {
                    float4 v = *(const float4*)(emb + (size_t)s_row[part][i] * E_ + cc);
                    float wv = s_w[part][i];
                    ax += wv * v.x; ay += wv * v.y; az += wv * v.z; aw += wv * v.w;
                }
            } else {
                for (int i = 0; i < 16; ++i) {
                    float4 v = *(const float4*)(doc_f + ((size_t)b * LD_ + s_t[part][i]) * NF_);
                    float wv = s_w[part][i];
                    ax += wv * v.x; ay += wv * v.y; az += wv * v.z; aw += wv * v.w;
                }
            }
            ushort4 o; o.x = f2bf(ax); o.y = f2bf(ay); o.z = f2bf(az); o.w = f2bf(aw);
            *(ushort4*)(out + 4 * g) = o;
        } else if (g < 303) {              // query FOFE, ce = (g-228)*4
            int ce = (g - 228) * 4;
            float ax = 0.f, ay = 0.f, az = 0.f, aw = 0.f;
            for (int i = 0; i < 32; ++i) {
                int row = query[b * LQ_ + i];
                float wv = A_POW[LQ_ - 1 - i];
                float4 v = *(const float4*)(emb + (size_t)row * E_ + ce);
                ax += wv * v.x; ay += wv * v.y; az += wv * v.z; aw += wv * v.w;
            }
            ushort4 o; o.x = f2bf(ax); o.y = f2bf(ay); o.z = f2bf(az); o.w = f2bf(aw);
            *(ushort4*)(out + 4 * g) = o;
        } else if (g == 303) {             // K padding 1212..1215
            ushort4 z; z.x = 0; z.y = 0; z.z = 0; z.w = 0;
            *(ushort4*)(out + 4 * g) = z;
        }
    } else if (bid < 2000) {
        const long n1 = 1024L * 304;                 // W1 groups (K-padded)
        const long n2 = 1024L * 1024L / 4;
        const long n4 = 512L * 1024L / 4;
        const long total = n1 + 2 * n2 + n4;
        long stride = 944L * 320L;
        for (long i = (long)(bid - NCOL_) * 320L + tid; i < total; i += stride) {
            ushort4 o;
            if (i < n1) {
                long m = i / 304; int k4 = (int)(i - m * 304);
                if (k4 < 303) {
                    float4 v = *(const float4*)(W1 + m * CIN_ + k4 * 4);
                    o.x = f2bf(v.x); o.y = f2bf(v.y); o.z = f2bf(v.z); o.w = f2bf(v.w);
                } else { o.x = 0; o.y = 0; o.z = 0; o.w = 0; }
                *(ushort4*)(W1b + i * 4) = o;
            } else if (i < n1 + n2) {
                long j = i - n1;
                float4 v = *(const float4*)(W2 + j * 4);
                o.x = f2bf(v.x); o.y = f2bf(v.y); o.z = f2bf(v.z); o.w = f2bf(v.w);
                *(ushort4*)(W2b + j * 4) = o;
            } else if (i < n1 + 2 * n2) {
                long j = i - n1 - n2;
                float4 v = *(const float4*)(W3 + j * 4);
                o.x = f2bf(v.x); o.y = f2bf(v.y); o.z = f2bf(v.z); o.w = f2bf(v.w);
                *(ushort4*)(W3b + j * 4) = o;
            } else {
                long j = i - n1 - 2 * n2;
                float4 v = *(const float4*)(W4 + j * 4);
                o.x = f2bf(v.x); o.y = f2bf(v.y); o.z = f2bf(v.z); o.w = f2bf(v.w);
                *(ushort4*)(W4b + j * 4) = o;
            }
        }
    } else if (bid < 2032) {
        int row = NCOL_ + (bid - 2000);
        if (tid < 304) {
            ushort4 z; z.x = 0; z.y = 0; z.z = 0; z.w = 0;
            *(ushort4*)(Ft + (size_t)row * KP1_ + tid * 4) = z;
        }
    } else {
        for (int i = tid; i < NPAD_; i += 320) zbuf[i] = 0.f;
        if (tid == 0) *done = 0u;
    }
}

// ---------------------------------------------------------------------------
// 32x64 GEMM core (L1-L3): BK=64, double-buffered LDS, 4 waves each 16x32
// (wm=(w&1)*16, wn=(w>>1)*32, 2 accs). Grid (M/32, N/64) = 544 blocks.
// ---------------------------------------------------------------------------
struct GemmS64 { unsigned short A[2][32][72]; unsigned short B[2][64][72]; };

__device__ __forceinline__ void gemm_core_3264(
    const unsigned short* __restrict__ A,
    const unsigned short* __restrict__ Bm,
    int K, int m0, int n0, GemmS64& sh, f32x4 acc[2])
{
    int tid = threadIdx.x;
    int w = tid >> 6, lane = tid & 63;
    int wm = (w & 1) * 16, wn = (w >> 1) * 32;
    int fr = lane & 15, fk = (lane >> 4) * 8;
    int arow = tid >> 3, acol = (tid & 7) * 8;     // A: 32x64, 1 uint4/thread
    int brow = tid >> 2, bcol = (tid & 3) * 16;    // B: 64x64, 2 uint4/thread

    const unsigned short* Ap = A + (size_t)(m0 + arow) * K + acol;
    const unsigned short* Bp = Bm + (size_t)(n0 + brow) * K + bcol;

    acc[0][0]=0.f; acc[0][1]=0.f; acc[0][2]=0.f; acc[0][3]=0.f;
    acc[1][0]=0.f; acc[1][1]=0.f; acc[1][2]=0.f; acc[1][3]=0.f;

    int nk = K >> 6;
    *(uint4*)&sh.A[0][arow][acol]     = *(const uint4*)(Ap);
    *(uint4*)&sh.B[0][brow][bcol]     = *(const uint4*)(Bp);
    *(uint4*)&sh.B[0][brow][bcol + 8] = *(const uint4*)(Bp + 8);
    __syncthreads();
    int cur = 0;
    for (int i = 0; i < nk; ++i) {
        uint4 na, nb0, nb1;
        bool more = (i + 1 < nk);
        if (more) {
            const unsigned short* An = Ap + (size_t)(i + 1) * 64;
            const unsigned short* Bn = Bp + (size_t)(i + 1) * 64;
            na  = *(const uint4*)(An);
            nb0 = *(const uint4*)(Bn);
            nb1 = *(const uint4*)(Bn + 8);
        }
        #pragma unroll
        for (int s = 0; s < 2; ++s) {
            short8 fa = *(const short8*)&sh.A[cur][wm + fr][s * 32 + fk];
            short8 fb0 = *(const short8*)&sh.B[cur][wn + fr][s * 32 + fk];
            short8 fb1 = *(const short8*)&sh.B[cur][wn + 16 + fr][s * 32 + fk];
            acc[0] = __builtin_amdgcn_mfma_f32_16x16x32_bf16(fa, fb0, acc[0], 0, 0, 0);
            acc[1] = __builtin_amdgcn_mfma_f32_16x16x32_bf16(fa, fb1, acc[1], 0, 0, 0);
        }
        if (more) {
            int nb = cur ^ 1;
            *(uint4*)&sh.A[nb][arow][acol]     = na;
            *(uint4*)&sh.B[nb][brow][bcol]     = nb0;
            *(uint4*)&sh.B[nb][brow][bcol + 8] = nb1;
        }
        __syncthreads();
        cur ^= 1;
    }
}

__global__ __launch_bounds__(256) void gemm_relu(
    const unsigned short* __restrict__ A,
    const unsigned short* __restrict__ Bm,
    unsigned short* __restrict__ C, int M, int K)
{
    __shared__ GemmS64 sh;
    int m0 = blockIdx.x * 32, n0 = blockIdx.y * 64;
    f32x4 acc[2];
    gemm_core_3264(A, Bm, K, m0, n0, sh, acc);
    int tid = threadIdx.x;
    int w = tid >> 6, lane = tid & 63;
    int wm = (w & 1) * 16, wn = (w >> 1) * 32;
    int rbase = (lane >> 4) * 4;
    int cb = lane & 15;
    #pragma unroll
    for (int nt = 0; nt < 2; ++nt) {
        int m = m0 + wm + rbase;
        int n = n0 + wn + nt * 16 + cb;
        ushort4 o;
        o.x = f2bf(fmaxf(acc[nt][0], 0.f));
        o.y = f2bf(fmaxf(acc[nt][1], 0.f));
        o.z = f2bf(fmaxf(acc[nt][2], 0.f));
        o.w = f2bf(fmaxf(acc[nt][3], 0.f));
        *(ushort4*)(C + (size_t)n * M + m) = o;
    }
}

// ---------------------------------------------------------------------------
// L4 (32x32 tiles) + score partials + loss-by-last-block. Grid (16,34)=544.
// z[n] += sum_m relu(h4[m][n]) * W5[m]; last block computes the loss.
// ---------------------------------------------------------------------------
struct GemmS32 { unsigned short A[2][32][72]; unsigned short B[2][32][72]; };

__global__ __launch_bounds__(256) void gemm4_score_loss(
    const unsigned short* __restrict__ A,
    const unsigned short* __restrict__ Bm,
    const float* __restrict__ W5, const int* __restrict__ rand_idx,
    float* __restrict__ zbuf, unsigned* __restrict__ done,
    float* __restrict__ out, int M, int K)
{
    __shared__ GemmS32 sh;
    __shared__ int s_flag;
    __shared__ int s_cnt[32];
    __shared__ float s_red[256];
    int tid = threadIdx.x;
    int w = tid >> 6, lane = tid & 63;
    int wm = (w & 1) * 16, wn = (w >> 1) * 16;
    int fr = lane & 15, fq = lane >> 4, fk = fq * 8;
    int arow = tid >> 3, acol = (tid & 7) * 8;     // 32x64 staging, 1 uint4
    int m0 = blockIdx.x * 32, n0 = blockIdx.y * 32;

    const unsigned short* Ap = A + (size_t)(m0 + arow) * K + acol;
    const unsigned short* Bp = Bm + (size_t)(n0 + arow) * K + acol;

    f32x4 acc = {0.f, 0.f, 0.f, 0.f};
    int nk = K >> 6;
    *(uint4*)&sh.A[0][arow][acol] = *(const uint4*)(Ap);
    *(uint4*)&sh.B[0][arow][acol] = *(const uint4*)(Bp);
    __syncthreads();
    int cur = 0;
    for (int i = 0; i < nk; ++i) {
        uint4 na, nb;
        bool more = (i + 1 < nk);
        if (more) {
            na = *(const uint4*)(Ap + (size_t)(i + 1) * 64);
            nb = *(const uint4*)(Bp + (size_t)(i + 1) * 64);
        }
        #pragma unroll
        for (int s = 0; s < 2; ++s) {
            short8 fa = *(const short8*)&sh.A[cur][wm + fr][s * 32 + fk];
            short8 fb = *(const short8*)&sh.B[cur][wn + fr][s * 32 + fk];
            acc = __builtin_amdgcn_mfma_f32_16x16x32_bf16(fa, fb, acc, 0, 0, 0);
        }
        if (more) {
            int nb2 = cur ^ 1;
            *(uint4*)&sh.A[nb2][arow][acol] = na;
            *(uint4*)&sh.B[nb2][arow][acol] = nb;
        }
        __syncthreads();
        cur ^= 1;
    }

    {   // score partial: p(fq,cb) = sum_i relu(acc[i]) * W5[m]
        int mb = m0 + wm + fq * 4;
        float p = fmaxf(acc[0], 0.f) * W5[mb]
                + fmaxf(acc[1], 0.f) * W5[mb + 1]
                + fmaxf(acc[2], 0.f) * W5[mb + 2]
                + fmaxf(acc[3], 0.f) * W5[mb + 3];
        p += __shfl_down(p, 32);
        p += __shfl_down(p, 16);
        if (fq == 0) {
            int n = n0 + wn + fr;
            atomicAdd(&zbuf[n], p);
        }
    }
    __syncthreads();
    if (tid == 0) {
        unsigned total = gridDim.x * gridDim.y;
        unsigned old = __hip_atomic_fetch_add(done, 1u, __ATOMIC_ACQ_REL,
                                              __HIP_MEMORY_SCOPE_AGENT);
        s_flag = (old == total - 1) ? 1 : 0;
    }
    __syncthreads();
    if (s_flag) {      // last block: all zbuf adds visible
        if (tid < 32) s_cnt[tid] = 0;
        __syncthreads();
        if (tid < NEG_N_) atomicAdd(&s_cnt[rand_idx[tid]], 1);
        __syncthreads();
        float accv = 0.f;
        for (int c = tid; c < NCOL_; c += 256) {
            float z = __hip_atomic_load(&zbuf[c], __ATOMIC_ACQUIRE,
                                        __HIP_MEMORY_SCOPE_AGENT);
            float s = 1.f / (1.f + expf(-z));
            int c33 = c % 33;
            if (c33 == 0) { float d = s - 1.f; accv += 128.f * d * d; }
            else          { accv += (float)s_cnt[c33 - 1] * s * s; }
        }
        s_red[tid] = accv;
        __syncthreads();
        for (int o = 128; o > 0; o >>= 1) {
            if (tid < o) s_red[tid] += s_red[tid + o];
            __syncthreads();
        }
        if (tid == 0) out[0] = s_red[0];
    }
}

extern "C" void kernel_launch(void* const* d_in, const int* in_sizes, int n_in,
                              void* d_out, int out_size, void* d_ws, size_t ws_size,
                              hipStream_t stream)
{
    const int*   doc        = (const int*)d_in[0];
    const float* doc_f      = (const float*)d_in[1];
    const int*   query      = (const int*)d_in[2];
    const int*   target_s   = (const int*)d_in[3];
    const int*   target_e   = (const int*)d_in[4];
    const float* emb        = (const float*)d_in[7];
    const float* W1         = (const float*)d_in[8];
    const float* W2         = (const float*)d_in[9];
    const float* W3         = (const float*)d_in[10];
    const float* W4         = (const float*)d_in[11];
    const float* W5         = (const float*)d_in[12];
    const int*   rand_length   = (const int*)d_in[13];
    const int*   rand_position = (const int*)d_in[14];
    const int*   rand_idx      = (const int*)d_in[15];

    char* ws = (char*)d_ws;
    size_t off = 0;
    auto alloc = [&](size_t bytes) {
        void* p = ws + off;
        off = (off + bytes + 255) & ~(size_t)255;
        return p;
    };
    unsigned short* W1b = (unsigned short*)alloc((size_t)1024 * KP1_ * 2);
    unsigned short* W2b = (unsigned short*)alloc((size_t)1024 * 1024 * 2);
    unsigned short* W3b = (unsigned short*)alloc((size_t)1024 * 1024 * 2);
    unsigned short* W4b = (unsigned short*)alloc((size_t)512 * 1024 * 2);
    unsigned short* Ft  = (unsigned short*)alloc((size_t)NPAD_ * KP1_ * 2);
    unsigned short* hA  = (unsigned short*)alloc((size_t)NPAD_ * 1024 * 2);
    unsigned short* hB  = (unsigned short*)alloc((size_t)NPAD_ * 1024 * 2);
    float*    zbuf      = (float*)alloc((size_t)NPAD_ * sizeof(float));
    unsigned* done      = (unsigned*)alloc(256);
    (void)ws_size; (void)in_sizes; (void)n_in; (void)out_size;

    prep<<<dim3(2033), dim3(320), 0, stream>>>(
        doc, doc_f, query, target_s, target_e, emb,
        rand_length, rand_position,
        W1, W2, W3, W4, W1b, W2b, W3b, W4b, Ft, zbuf, done);

    gemm_relu<<<dim3(32, 17), dim3(256), 0, stream>>>(W1b, Ft, hA, 1024, KP1_);
    gemm_relu<<<dim3(32, 17), dim3(256), 0, stream>>>(W2b, hA, hB, 1024, 1024);
    gemm_relu<<<dim3(32, 17), dim3(256), 0, stream>>>(W3b, hB, hA, 1024, 1024);
    gemm4_score_loss<<<dim3(16, 34), dim3(256), 0, stream>>>(
        W4b, hA, W5, rand_idx, zbuf, done, (float*)d_out, 512, 1024);
}